// Round 4
// baseline (3086.875 us; speedup 1.0000x reference)
//
#include <hip/hip_runtime.h>

#define NPTS 80000
#define MPTS 150000
#define NDPTS 10000
#define KOFF 27
#define C3 16
#define CP 259
#define C2 64
#define CM 80
#define CO 96

typedef __attribute__((ext_vector_type(8))) short short8;
typedef __attribute__((ext_vector_type(4))) float f32x4;

__device__ inline short bf16r(float f) {
  union { float f; unsigned u; } x{f};
  unsigned r = (x.u + 0x7fffu + ((x.u >> 16) & 1u)) >> 16;
  return (short)r;
}

// ---------------------------------------------------------------------------
// Weight prep: W[k][ci][n] fp32 -> fragment-ordered bf16
// WbfF[((k*KC+q)*NT+t)*512 + lane*8 + j], where B-frag element is
// ci = q*32 + (lane>>4)*8 + j, n = t*16 + (lane&15); ci >= CIN zero-padded.
// ---------------------------------------------------------------------------
__global__ void wfrag_kernel(const float* __restrict__ W, short* __restrict__ WbfF,
                             int CIN, int COUT_, int KC) {
  const int NT = COUT_ / 16;
  int i = blockIdx.x * 256 + threadIdx.x;
  int total = KOFF * KC * NT * 512;
  if (i >= total) return;
  int j = i & 7, lane = (i >> 3) & 63;
  int rest = i >> 9;
  int t = rest % NT; rest /= NT;
  int q = rest % KC;
  int k = rest / KC;
  int ci = q * 32 + (lane >> 4) * 8 + j;
  int n = t * 16 + (lane & 15);
  float v = (ci < CIN) ? W[((size_t)k * CIN + ci) * COUT_ + n] : 0.f;
  WbfF[i] = bf16r(v);
}

// ---------------------------------------------------------------------------
// Wp prep: fp32 [259][64] -> bf16 fragment-ordered [q][t][lane][8], K padded
// to 288 (9 chunks of 32).
// ---------------------------------------------------------------------------
__global__ void wpfrag_kernel(const float* __restrict__ Wp, short* __restrict__ WpF) {
  int i = blockIdx.x * 256 + threadIdx.x;
  if (i >= 9 * 4 * 64 * 8) return;
  int j = i & 7, lane = (i >> 3) & 63, t = (i >> 9) & 3, q = i >> 11;
  int k = q * 32 + (lane >> 4) * 8 + j;
  int n = t * 16 + (lane & 15);
  WpF[i] = (k < CP) ? bf16r(Wp[(size_t)k * C2 + n]) : (short)0;
}

// ---------------------------------------------------------------------------
// Kernel 1: conv3d (16->16) + bn_relu. Writes y3d (fp32), mix[:, :16] (fp32)
// and mixbf[:, :16] (bf16).
// ---------------------------------------------------------------------------
__global__ __launch_bounds__(256) void conv3d_bnrelu_kernel(
    const float* __restrict__ x3d, const int* __restrict__ nbr,
    const float* __restrict__ W3d, const float* __restrict__ g3d,
    const float* __restrict__ b3d, float* __restrict__ y3d,
    float* __restrict__ mix, short* __restrict__ mixbf)
{
  __shared__ float wS[KOFF * C3 * C3];
  __shared__ float fS[16][C3];
  const int tid = threadIdx.x;
  const int base = blockIdx.x * 16;
  for (int e = tid; e < KOFF * C3 * C3; e += 256) wS[e] = W3d[e];
  const int r = tid >> 4, c = tid & 15;
  const int row = base + r;
  float acc = 0.f;
  for (int k = 0; k < KOFF; ++k) {
    int idx = nbr[row * KOFF + k];
    float fv = (idx >= 0) ? x3d[idx * C3 + c] : 0.f;
    __syncthreads();
    fS[r][c] = fv;
    __syncthreads();
    const float* wk = &wS[k * C3 * C3];
    #pragma unroll
    for (int ci = 0; ci < C3; ++ci)
      acc = fmaf(fS[r][ci], wk[ci * C3 + c], acc);
  }
  float v = fmaxf(fmaf(acc, g3d[c], b3d[c]), 0.f);
  y3d[row * C3 + c] = v;
  mix[row * CM + c] = v;
  mixbf[row * CM + c] = bf16r(v);
}

// ---------------------------------------------------------------------------
// Kernel 2: gate/cross fusion (unchanged from round 3).
// ---------------------------------------------------------------------------
__global__ __launch_bounds__(256) void gate_cross_mfma_kernel(
    const float* __restrict__ y3d, const float* __restrict__ f2d,
    const int* __restrict__ nn_idx,
    const float* __restrict__ Wg, const float* __restrict__ bg,
    const float* __restrict__ Wc, const float* __restrict__ bc,
    const short* __restrict__ WpF,
    short* __restrict__ p2dbf, float* __restrict__ cross2d)
{
  constexpr int RS = 296;
  __shared__ short g1S[32 * RS];
  __shared__ short g2S[32 * RS];
  const int tid = threadIdx.x;
  const int lane = tid & 63;
  const int w = tid >> 6;
  const int lm = lane & 15;
  const int quad = lane >> 4;
  const int base = blockIdx.x * 32;

  for (int e = tid; e < 32 * 32; e += 256) {
    int r = e >> 5, cc = 256 + (e & 31);
    if (cc >= CP) {
      g1S[r * RS + cc] = 0;
      g2S[r * RS + cc] = 0;
    }
  }

  {
    const int c = tid;
    float wg[16], wc[16];
    #pragma unroll
    for (int ci = 0; ci < 16; ++ci) {
      wg[ci] = Wg[ci * CP + c];
      wc[ci] = Wc[ci * CP + c];
    }
    const float bgv = bg[c], bcv = bc[c];
    for (int r = 0; r < 32; ++r) {
      const int row = base + r;
      const int idx = nn_idx[row];
      const float* yr = y3d + (size_t)row * C3;
      float f = (idx >= 0) ? f2d[(size_t)idx * CP + c] : 0.f;
      float a1 = bgv, a2 = bcv;
      #pragma unroll
      for (int ci = 0; ci < 16; ++ci) {
        float yv = yr[ci];
        a1 = fmaf(yv, wg[ci], a1);
        a2 = fmaf(yv, wc[ci], a2);
      }
      g1S[r * RS + c] = bf16r(fmaxf(a1, 0.f) * f);
      g2S[r * RS + c] = bf16r(fmaxf(a2, 0.f) * f);
    }
  }
  if (w == 0 && lane < 3) {
    const int c = 256 + lane;
    float wg[16], wc[16];
    #pragma unroll
    for (int ci = 0; ci < 16; ++ci) {
      wg[ci] = Wg[ci * CP + c];
      wc[ci] = Wc[ci * CP + c];
    }
    const float bgv = bg[c], bcv = bc[c];
    for (int r = 0; r < 32; ++r) {
      const int row = base + r;
      const int idx = nn_idx[row];
      const float* yr = y3d + (size_t)row * C3;
      float f = (idx >= 0) ? f2d[(size_t)idx * CP + c] : 0.f;
      float a1 = bgv, a2 = bcv;
      #pragma unroll
      for (int ci = 0; ci < 16; ++ci) {
        float yv = yr[ci];
        a1 = fmaf(yv, wg[ci], a1);
        a2 = fmaf(yv, wc[ci], a2);
      }
      g1S[r * RS + c] = bf16r(fmaxf(a1, 0.f) * f);
      g2S[r * RS + c] = bf16r(fmaxf(a2, 0.f) * f);
    }
  }
  __syncthreads();

  const int gsel = w & 1;
  const int mt = w >> 1;
  const short* gS = gsel ? g2S : g1S;
  f32x4 acc[4];
  #pragma unroll
  for (int t = 0; t < 4; ++t) {
    f32x4 z = {0.f, 0.f, 0.f, 0.f};
    acc[t] = z;
  }
  #pragma unroll
  for (int q = 0; q < 9; ++q) {
    short8 af = *(const short8*)&gS[(mt * 16 + lm) * RS + q * 32 + quad * 8];
    #pragma unroll
    for (int t = 0; t < 4; ++t) {
      short8 bf = *(const short8*)&WpF[(((q * 4 + t) * 64) + lane) * 8];
      acc[t] = __builtin_amdgcn_mfma_f32_16x16x32_bf16(af, bf, acc[t], 0, 0, 0);
    }
  }
  #pragma unroll
  for (int t = 0; t < 4; ++t) {
    const int c = t * 16 + lm;
    #pragma unroll
    for (int rg = 0; rg < 4; ++rg) {
      const int row = base + mt * 16 + quad * 4 + rg;
      float v = acc[t][rg];
      if (gsel == 0)
        p2dbf[(size_t)row * C2 + c] = bf16r(v);
      else
        cross2d[(size_t)row * C2 + c] = v;
    }
  }
}

// ---------------------------------------------------------------------------
// Barrier-free direct-gather MFMA subm-conv.
// Block = 4 waves x 32 rows = 128 rows. No LDS. Each lane gathers its own
// A-fragment (A row = lane&15, chunk = quad): 16 B/lane, 4 quads = 64 B of a
// gathered row. B-fragments from fragment-ordered global weights (coalesced,
// L1-resident). Software pipeline: idx prefetch dist 2, A-gather dist 1 —
// loads stay in flight across k (no barriers anywhere).
// MODE 0: bn_relu -> fp32    MODE 1: bn_relu -> bf16
// MODE 2: relu(bn)+res(stride 64) -> fp32 mix[:,16+c] + bf16 mixbf
// MODE 3: relu(bn+res) -> fp32 + bf16    MODE 4: relu(bn+res) -> bf16
// ---------------------------------------------------------------------------
template <int CIN, int COUT_, int KC, int MODE>
__global__ __launch_bounds__(256) void conv_gmfma_kernel(
    const short* __restrict__ finbf, const int* __restrict__ nbr, int nrows,
    const short* __restrict__ WbfF, const float* __restrict__ gamma,
    const float* __restrict__ beta, const float* __restrict__ resf,
    float* __restrict__ outf, short* __restrict__ outbf)
{
  constexpr int NT = COUT_ / 16;
  constexpr int MT = 2;
  const int tid = threadIdx.x;
  const int lane = tid & 63;
  const int w = tid >> 6;
  const int lm = lane & 15;
  const int quad = lane >> 4;
  const int base = blockIdx.x * 128 + w * 32;
  const int colb = quad * 8;           // byte-chunk col base within 32-wide chunk

  int arow[MT];
  #pragma unroll
  for (int i = 0; i < MT; ++i) arow[i] = base + i * 16 + lm;

  f32x4 acc[MT][NT];
  #pragma unroll
  for (int i = 0; i < MT; ++i)
    #pragma unroll
    for (int t = 0; t < NT; ++t) {
      f32x4 z = {0.f, 0.f, 0.f, 0.f};
      acc[i][t] = z;
    }

  int idxb[2][MT];
  short8 ab[2][MT][KC];
  const short8 zero8 = {0, 0, 0, 0, 0, 0, 0, 0};

#define LOAD_IDX(K, B)                                                   \
  _Pragma("unroll") for (int i = 0; i < MT; ++i) {                       \
    idxb[B][i] = (arow[i] < nrows) ? nbr[(size_t)arow[i] * KOFF + (K)] : -1; \
  }
#define LOAD_A(B)                                                        \
  _Pragma("unroll") for (int i = 0; i < MT; ++i) {                       \
    int ix = idxb[B][i];                                                 \
    _Pragma("unroll") for (int q = 0; q < KC; ++q) {                     \
      bool valid = (ix >= 0) && (q * 32 + colb < CIN);                   \
      ab[B][i][q] = valid                                                \
          ? *(const short8*)&finbf[(size_t)ix * CIN + q * 32 + colb]     \
          : zero8;                                                       \
    }                                                                    \
  }

  LOAD_IDX(0, 0)
  LOAD_A(0)
  LOAD_IDX(1, 1)

  for (int k = 0; k < KOFF; ++k) {
    const int cur = k & 1, nxt = cur ^ 1;
    if (k + 1 < KOFF) { LOAD_A(nxt) }
    if (k + 2 < KOFF) { LOAD_IDX(k + 2, cur) }
    #pragma unroll
    for (int q = 0; q < KC; ++q) {
      short8 bfrag[NT];
      #pragma unroll
      for (int t = 0; t < NT; ++t)
        bfrag[t] = *(const short8*)&WbfF[(size_t)(((k * KC + q) * NT + t) * 512) + lane * 8];
      #pragma unroll
      for (int i = 0; i < MT; ++i)
        #pragma unroll
        for (int t = 0; t < NT; ++t)
          acc[i][t] = __builtin_amdgcn_mfma_f32_16x16x32_bf16(
              ab[cur][i][q], bfrag[t], acc[i][t], 0, 0, 0);
    }
  }
#undef LOAD_IDX
#undef LOAD_A

  // ---- epilogue ----
  #pragma unroll
  for (int i = 0; i < MT; ++i) {
    int rbase = base + i * 16 + quad * 4;
    #pragma unroll
    for (int t = 0; t < NT; ++t) {
      int c = t * 16 + lm;
      float g = gamma[c], b = beta[c];
      #pragma unroll
      for (int rg = 0; rg < 4; ++rg) {
        int row = rbase + rg;
        if (row >= nrows) continue;
        float v = acc[i][t][rg];
        if (MODE == 0) {
          outf[(size_t)row * COUT_ + c] = fmaxf(fmaf(v, g, b), 0.f);
        } else if (MODE == 1) {
          outbf[(size_t)row * COUT_ + c] = bf16r(fmaxf(fmaf(v, g, b), 0.f));
        } else if (MODE == 2) {
          float o = fmaxf(fmaf(v, g, b), 0.f) + resf[(size_t)row * C2 + c];
          outf[(size_t)row * CM + 16 + c] = o;
          outbf[(size_t)row * CM + 16 + c] = bf16r(o);
        } else if (MODE == 3) {
          float o = fmaxf(fmaf(v, g, b) + resf[(size_t)row * COUT_ + c], 0.f);
          outf[(size_t)row * COUT_ + c] = o;
          outbf[(size_t)row * COUT_ + c] = bf16r(o);
        } else {
          float o = fmaxf(fmaf(v, g, b) + resf[(size_t)row * COUT_ + c], 0.f);
          outbf[(size_t)row * COUT_ + c] = bf16r(o);
        }
      }
    }
  }
}

// ---------------------------------------------------------------------------
extern "C" void kernel_launch(void* const* d_in, const int* in_sizes, int n_in,
                              void* d_out, int out_size, void* d_ws, size_t ws_size,
                              hipStream_t stream) {
  const float* x3d  = (const float*)d_in[0];
  const float* f2d  = (const float*)d_in[1];
  const int*   nn   = (const int*)d_in[2];
  const int*   nbr  = (const int*)d_in[3];
  const int*   nbds = (const int*)d_in[4];
  const float* W3d  = (const float*)d_in[5];
  const float* g3d  = (const float*)d_in[6];
  const float* b3d  = (const float*)d_in[7];
  const float* Wg   = (const float*)d_in[8];
  const float* bg   = (const float*)d_in[9];
  const float* Wc   = (const float*)d_in[10];
  const float* bc   = (const float*)d_in[11];
  const float* Wp   = (const float*)d_in[12];
  const float* W2d  = (const float*)d_in[13];
  const float* g2d  = (const float*)d_in[14];
  const float* b2d  = (const float*)d_in[15];
  const float* Wm1  = (const float*)d_in[16];
  const float* gm1  = (const float*)d_in[17];
  const float* bm1  = (const float*)d_in[18];
  const float* Wm2  = (const float*)d_in[19];
  const float* gm2  = (const float*)d_in[20];
  const float* bm2  = (const float*)d_in[21];
  const float* Wa1  = (const float*)d_in[22];
  const float* ga1  = (const float*)d_in[23];
  const float* ba1  = (const float*)d_in[24];
  const float* Wa2  = (const float*)d_in[25];
  const float* ga2  = (const float*)d_in[26];
  const float* ba2  = (const float*)d_in[27];
  const float* Wds  = (const float*)d_in[28];
  const float* gds  = (const float*)d_in[29];
  const float* bds  = (const float*)d_in[30];

  const size_t N = NPTS;
  float* ws = (float*)d_ws;
  float* y3d     = ws;                    // N*16
  short* p2dbf   = (short*)(ws + N * 16); // N*64 bf16
  float* cross2d = ws + N * 48;           // N*64
  float* mix     = ws + N * 112;          // N*80
  short* mixbf   = (short*)(ws + N * 192);// N*80 bf16
  short* tmp1bf  = (short*)(ws + N * 232);// N*80 bf16
  float* hbuf    = ws + N * 272;          // N*80
  short* hbufbf  = (short*)(ws + N * 352);// N*80 bf16
  short* abufbf  = (short*)ws;            // N*80 bf16 (reuses y3d+p2dbf)
  // fragment-ordered bf16 weights at tail (sizes match round-3 layout)
  short* wtail  = (short*)(ws + N * 392);
  short* WbfF2d = wtail;                   // 27*2*4*512 = 110592
  short* WbfFm1 = WbfF2d + 110592;         // 27*3*5*512 = 207360
  short* WbfFm2 = WbfFm1 + 207360;
  short* WbfFa1 = WbfFm2 + 207360;
  short* WbfFa2 = WbfFa1 + 207360;
  short* WbfFds = WbfFa2 + 207360;         // 27*3*6*512 = 248832
  short* WpF    = WbfFds + 248832;         // 18432

  // ---- weight prep ----
  wfrag_kernel<<<(110592 + 255) / 256, 256, 0, stream>>>(W2d, WbfF2d, 64, 64, 2);
  wfrag_kernel<<<(207360 + 255) / 256, 256, 0, stream>>>(Wm1, WbfFm1, 80, 80, 3);
  wfrag_kernel<<<(207360 + 255) / 256, 256, 0, stream>>>(Wm2, WbfFm2, 80, 80, 3);
  wfrag_kernel<<<(207360 + 255) / 256, 256, 0, stream>>>(Wa1, WbfFa1, 80, 80, 3);
  wfrag_kernel<<<(207360 + 255) / 256, 256, 0, stream>>>(Wa2, WbfFa2, 80, 80, 3);
  wfrag_kernel<<<(248832 + 255) / 256, 256, 0, stream>>>(Wds, WbfFds, 80, 96, 3);
  wpfrag_kernel<<<(9 * 4 * 64 * 8 + 255) / 256, 256, 0, stream>>>(Wp, WpF);

  conv3d_bnrelu_kernel<<<NPTS / 16, 256, 0, stream>>>(x3d, nbr, W3d, g3d, b3d,
                                                      y3d, mix, mixbf);
  gate_cross_mfma_kernel<<<NPTS / 32, 256, 0, stream>>>(y3d, f2d, nn, Wg, bg,
                                                        Wc, bc, WpF, p2dbf,
                                                        cross2d);

  const int gridN = (NPTS + 127) / 128;    // 625
  conv_gmfma_kernel<64, 64, 2, 2><<<gridN, 256, 0, stream>>>(
      p2dbf, nbr, NPTS, WbfF2d, g2d, b2d, cross2d, mix, mixbf);
  conv_gmfma_kernel<80, 80, 3, 1><<<gridN, 256, 0, stream>>>(
      mixbf, nbr, NPTS, WbfFm1, gm1, bm1, nullptr, nullptr, tmp1bf);
  conv_gmfma_kernel<80, 80, 3, 3><<<gridN, 256, 0, stream>>>(
      tmp1bf, nbr, NPTS, WbfFm2, gm2, bm2, mix, hbuf, hbufbf);
  conv_gmfma_kernel<80, 80, 3, 1><<<gridN, 256, 0, stream>>>(
      hbufbf, nbr, NPTS, WbfFa1, ga1, ba1, nullptr, nullptr, tmp1bf);
  conv_gmfma_kernel<80, 80, 3, 4><<<gridN, 256, 0, stream>>>(
      tmp1bf, nbr, NPTS, WbfFa2, ga2, ba2, hbuf, nullptr, abufbf);

  const int gridND = (NDPTS + 127) / 128;  // 79
  conv_gmfma_kernel<80, 96, 3, 0><<<gridND, 256, 0, stream>>>(
      abufbf, nbds, NDPTS, WbfFds, gds, bds, nullptr, (float*)d_out, nullptr);
}

// Round 5
// 1143.760 us; speedup vs baseline: 2.6989x; 2.6989x over previous
//
#include <hip/hip_runtime.h>

#define NPTS 80000
#define MPTS 150000
#define NDPTS 10000
#define KOFF 27
#define C3 16
#define CP 259
#define C2 64
#define CM 80
#define CO 96

typedef __attribute__((ext_vector_type(8))) short short8;
typedef __attribute__((ext_vector_type(4))) float f32x4;

__device__ inline short bf16r(float f) {
  union { float f; unsigned u; } x{f};
  unsigned r = (x.u + 0x7fffu + ((x.u >> 16) & 1u)) >> 16;
  return (short)r;
}

// ---------------------------------------------------------------------------
// Weight prep: W[k][ci][n] fp32 -> fragment-ordered bf16
// WbfF[((k*KC+q)*NT+t)*512 + lane*8 + j], B-frag element:
// ci = q*32 + (lane>>4)*8 + j, n = t*16 + (lane&15); ci >= CIN zero-padded.
// ---------------------------------------------------------------------------
__global__ void wfrag_kernel(const float* __restrict__ W, short* __restrict__ WbfF,
                             int CIN, int COUT_, int KC) {
  const int NT = COUT_ / 16;
  int i = blockIdx.x * 256 + threadIdx.x;
  int total = KOFF * KC * NT * 512;
  if (i >= total) return;
  int j = i & 7, lane = (i >> 3) & 63;
  int rest = i >> 9;
  int t = rest % NT; rest /= NT;
  int q = rest % KC;
  int k = rest / KC;
  int ci = q * 32 + (lane >> 4) * 8 + j;
  int n = t * 16 + (lane & 15);
  float v = (ci < CIN) ? W[((size_t)k * CIN + ci) * COUT_ + n] : 0.f;
  WbfF[i] = bf16r(v);
}

// ---------------------------------------------------------------------------
// Wp prep: fp32 [259][64] -> bf16 fragment-ordered [q][t][lane][8], K->288.
// ---------------------------------------------------------------------------
__global__ void wpfrag_kernel(const float* __restrict__ Wp, short* __restrict__ WpF) {
  int i = blockIdx.x * 256 + threadIdx.x;
  if (i >= 9 * 4 * 64 * 8) return;
  int j = i & 7, lane = (i >> 3) & 63, t = (i >> 9) & 3, q = i >> 11;
  int k = q * 32 + (lane >> 4) * 8 + j;
  int n = t * 16 + (lane & 15);
  WpF[i] = (k < CP) ? bf16r(Wp[(size_t)k * C2 + n]) : (short)0;
}

// ---------------------------------------------------------------------------
// Kernel 1: conv3d (16->16) + bn_relu -> y3d fp32, mix[:, :16], mixbf[:, :16].
// ---------------------------------------------------------------------------
__global__ __launch_bounds__(256) void conv3d_bnrelu_kernel(
    const float* __restrict__ x3d, const int* __restrict__ nbr,
    const float* __restrict__ W3d, const float* __restrict__ g3d,
    const float* __restrict__ b3d, float* __restrict__ y3d,
    float* __restrict__ mix, short* __restrict__ mixbf)
{
  __shared__ float wS[KOFF * C3 * C3];
  __shared__ float fS[16][C3];
  const int tid = threadIdx.x;
  const int base = blockIdx.x * 16;
  for (int e = tid; e < KOFF * C3 * C3; e += 256) wS[e] = W3d[e];
  const int r = tid >> 4, c = tid & 15;
  const int row = base + r;
  float acc = 0.f;
  for (int k = 0; k < KOFF; ++k) {
    int idx = nbr[row * KOFF + k];
    float fv = (idx >= 0) ? x3d[idx * C3 + c] : 0.f;
    __syncthreads();
    fS[r][c] = fv;
    __syncthreads();
    const float* wk = &wS[k * C3 * C3];
    #pragma unroll
    for (int ci = 0; ci < C3; ++ci)
      acc = fmaf(fS[r][ci], wk[ci * C3 + c], acc);
  }
  float v = fmaxf(fmaf(acc, g3d[c], b3d[c]), 0.f);
  y3d[row * C3 + c] = v;
  mix[row * CM + c] = v;
  mixbf[row * CM + c] = bf16r(v);
}

// ---------------------------------------------------------------------------
// Kernel 2: gate/cross fusion (unchanged from round 3).
// ---------------------------------------------------------------------------
__global__ __launch_bounds__(256) void gate_cross_mfma_kernel(
    const float* __restrict__ y3d, const float* __restrict__ f2d,
    const int* __restrict__ nn_idx,
    const float* __restrict__ Wg, const float* __restrict__ bg,
    const float* __restrict__ Wc, const float* __restrict__ bc,
    const short* __restrict__ WpF,
    short* __restrict__ p2dbf, float* __restrict__ cross2d)
{
  constexpr int RS = 296;
  __shared__ short g1S[32 * RS];
  __shared__ short g2S[32 * RS];
  const int tid = threadIdx.x;
  const int lane = tid & 63;
  const int w = tid >> 6;
  const int lm = lane & 15;
  const int quad = lane >> 4;
  const int base = blockIdx.x * 32;

  for (int e = tid; e < 32 * 32; e += 256) {
    int r = e >> 5, cc = 256 + (e & 31);
    if (cc >= CP) {
      g1S[r * RS + cc] = 0;
      g2S[r * RS + cc] = 0;
    }
  }

  {
    const int c = tid;
    float wg[16], wc[16];
    #pragma unroll
    for (int ci = 0; ci < 16; ++ci) {
      wg[ci] = Wg[ci * CP + c];
      wc[ci] = Wc[ci * CP + c];
    }
    const float bgv = bg[c], bcv = bc[c];
    for (int r = 0; r < 32; ++r) {
      const int row = base + r;
      const int idx = nn_idx[row];
      const float* yr = y3d + (size_t)row * C3;
      float f = (idx >= 0) ? f2d[(size_t)idx * CP + c] : 0.f;
      float a1 = bgv, a2 = bcv;
      #pragma unroll
      for (int ci = 0; ci < 16; ++ci) {
        float yv = yr[ci];
        a1 = fmaf(yv, wg[ci], a1);
        a2 = fmaf(yv, wc[ci], a2);
      }
      g1S[r * RS + c] = bf16r(fmaxf(a1, 0.f) * f);
      g2S[r * RS + c] = bf16r(fmaxf(a2, 0.f) * f);
    }
  }
  if (w == 0 && lane < 3) {
    const int c = 256 + lane;
    float wg[16], wc[16];
    #pragma unroll
    for (int ci = 0; ci < 16; ++ci) {
      wg[ci] = Wg[ci * CP + c];
      wc[ci] = Wc[ci * CP + c];
    }
    const float bgv = bg[c], bcv = bc[c];
    for (int r = 0; r < 32; ++r) {
      const int row = base + r;
      const int idx = nn_idx[row];
      const float* yr = y3d + (size_t)row * C3;
      float f = (idx >= 0) ? f2d[(size_t)idx * CP + c] : 0.f;
      float a1 = bgv, a2 = bcv;
      #pragma unroll
      for (int ci = 0; ci < 16; ++ci) {
        float yv = yr[ci];
        a1 = fmaf(yv, wg[ci], a1);
        a2 = fmaf(yv, wc[ci], a2);
      }
      g1S[r * RS + c] = bf16r(fmaxf(a1, 0.f) * f);
      g2S[r * RS + c] = bf16r(fmaxf(a2, 0.f) * f);
    }
  }
  __syncthreads();

  const int gsel = w & 1;
  const int mt = w >> 1;
  const short* gS = gsel ? g2S : g1S;
  f32x4 acc[4];
  #pragma unroll
  for (int t = 0; t < 4; ++t) {
    f32x4 z = {0.f, 0.f, 0.f, 0.f};
    acc[t] = z;
  }
  #pragma unroll
  for (int q = 0; q < 9; ++q) {
    short8 af = *(const short8*)&gS[(mt * 16 + lm) * RS + q * 32 + quad * 8];
    #pragma unroll
    for (int t = 0; t < 4; ++t) {
      short8 bf = *(const short8*)&WpF[(((q * 4 + t) * 64) + lane) * 8];
      acc[t] = __builtin_amdgcn_mfma_f32_16x16x32_bf16(af, bf, acc[t], 0, 0, 0);
    }
  }
  #pragma unroll
  for (int t = 0; t < 4; ++t) {
    const int c = t * 16 + lm;
    #pragma unroll
    for (int rg = 0; rg < 4; ++rg) {
      const int row = base + mt * 16 + quad * 4 + rg;
      float v = acc[t][rg];
      if (gsel == 0)
        p2dbf[(size_t)row * C2 + c] = bf16r(v);
      else
        cross2d[(size_t)row * C2 + c] = v;
    }
  }
}

// ---------------------------------------------------------------------------
// Double-buffered MFMA subm-conv, ONE barrier per k-iter.
// Block = 128 rows, 4 waves (MT=2 m-tiles x NT n-tiles per wave).
// A gathered with round-3's coalesced chunk mapping (consecutive lanes ->
// consecutive 16B chunks of the same row) into regs at iter top, MFMA runs
// from LDS buf[cur] (loads in flight underneath), then regs -> buf[cur^1],
// sync. B-fragments straight from fragment-ordered global (coalesced, L1-hot).
// LDS: 2 x 128 x AS shorts (CM: 53.2 KB -> 3 blocks/CU; C2: 36.9 KB -> 4).
// MODE 0: bn_relu -> fp32    MODE 1: bn_relu -> bf16
// MODE 2: relu(bn)+res(stride 64) -> fp32 mix[:,16+c] + bf16 mixbf
// MODE 3: relu(bn+res) -> fp32 + bf16    MODE 4: relu(bn+res) -> bf16
// ---------------------------------------------------------------------------
template <int CIN, int COUT_, int MODE, int MINW>
__global__ __launch_bounds__(256, MINW) void conv_db_kernel(
    const short* __restrict__ finbf, const int* __restrict__ nbr, int nrows,
    const short* __restrict__ WbfF, const float* __restrict__ gamma,
    const float* __restrict__ beta, const float* __restrict__ resf,
    float* __restrict__ outf, short* __restrict__ outbf)
{
  constexpr int KC = (CIN + 31) / 32;
  constexpr int KC32 = KC * 32;
  constexpr int AS = KC32 + 8;        // LDS row stride (shorts)
  constexpr int PCH = KC32 / 8;       // 16B chunks per padded row
  constexpr int DCH = CIN / 8;        // 16B chunks with real data
  constexpr int NT = COUT_ / 16;
  constexpr int MT = 2;
  constexpr int ROWS = 128;
  constexpr int AR = ROWS * PCH / 256;  // chunks per thread (4 or 6)

  __shared__ short fA[2][ROWS * AS];

  const int tid = threadIdx.x;
  const int lane = tid & 63;
  const int w = tid >> 6;
  const int lm = lane & 15;
  const int quad = lane >> 4;
  const int base = blockIdx.x * ROWS;

  // staging coordinates (hoisted out of the k-loop)
  int ar[AR], ac[AR];
  #pragma unroll
  for (int i = 0; i < AR; ++i) {
    int j = tid + i * 256;
    ar[i] = j / PCH;
    ac[i] = j - ar[i] * PCH;
  }

  f32x4 acc[MT][NT];
  #pragma unroll
  for (int i = 0; i < MT; ++i)
    #pragma unroll
    for (int t = 0; t < NT; ++t) {
      f32x4 z = {0.f, 0.f, 0.f, 0.f};
      acc[i][t] = z;
    }

  const short8 zero8 = {0, 0, 0, 0, 0, 0, 0, 0};
  short8 pa[AR];

  // ---- prologue: stage k=0 ----
  #pragma unroll
  for (int i = 0; i < AR; ++i) {
    int row = base + ar[i];
    int ix = (row < nrows) ? nbr[(size_t)row * KOFF] : -1;
    pa[i] = (ix >= 0 && ac[i] < DCH)
        ? *(const short8*)&finbf[(size_t)ix * CIN + ac[i] * 8] : zero8;
  }
  #pragma unroll
  for (int i = 0; i < AR; ++i)
    *(short8*)&fA[0][ar[i] * AS + ac[i] * 8] = pa[i];
  __syncthreads();

  for (int k = 0; k < KOFF; ++k) {
    const int cur = k & 1;
    // prefetch k+1 gathers into regs (stay in flight under the MFMAs)
    if (k + 1 < KOFF) {
      #pragma unroll
      for (int i = 0; i < AR; ++i) {
        int row = base + ar[i];
        int ix = (row < nrows) ? nbr[(size_t)row * KOFF + k + 1] : -1;
        pa[i] = (ix >= 0 && ac[i] < DCH)
            ? *(const short8*)&finbf[(size_t)ix * CIN + ac[i] * 8] : zero8;
      }
    }
    // MFMA from buf[cur]; B-frags from global (coalesced, L1-hot)
    #pragma unroll
    for (int q = 0; q < KC; ++q) {
      short8 afr[MT];
      #pragma unroll
      for (int i = 0; i < MT; ++i)
        afr[i] = *(const short8*)&fA[cur][((w * MT + i) * 16 + lm) * AS +
                                          q * 32 + quad * 8];
      #pragma unroll
      for (int t = 0; t < NT; ++t) {
        short8 bfr = *(const short8*)&WbfF[(size_t)(((k * KC + q) * NT + t) * 512) +
                                           lane * 8];
        #pragma unroll
        for (int i = 0; i < MT; ++i)
          acc[i][t] = __builtin_amdgcn_mfma_f32_16x16x32_bf16(afr[i], bfr,
                                                              acc[i][t], 0, 0, 0);
      }
    }
    // write prefetched tile to the other buffer, single barrier
    if (k + 1 < KOFF) {
      #pragma unroll
      for (int i = 0; i < AR; ++i)
        *(short8*)&fA[cur ^ 1][ar[i] * AS + ac[i] * 8] = pa[i];
    }
    __syncthreads();
  }

  // ---- epilogue ----
  #pragma unroll
  for (int i = 0; i < MT; ++i) {
    int rbase = base + (w * MT + i) * 16 + quad * 4;
    #pragma unroll
    for (int t = 0; t < NT; ++t) {
      int c = t * 16 + lm;
      float g = gamma[c], b = beta[c];
      #pragma unroll
      for (int rg = 0; rg < 4; ++rg) {
        int row = rbase + rg;
        if (row >= nrows) continue;
        float v = acc[i][t][rg];
        if (MODE == 0) {
          outf[(size_t)row * COUT_ + c] = fmaxf(fmaf(v, g, b), 0.f);
        } else if (MODE == 1) {
          outbf[(size_t)row * COUT_ + c] = bf16r(fmaxf(fmaf(v, g, b), 0.f));
        } else if (MODE == 2) {
          float o = fmaxf(fmaf(v, g, b), 0.f) + resf[(size_t)row * C2 + c];
          outf[(size_t)row * CM + 16 + c] = o;
          outbf[(size_t)row * CM + 16 + c] = bf16r(o);
        } else if (MODE == 3) {
          float o = fmaxf(fmaf(v, g, b) + resf[(size_t)row * COUT_ + c], 0.f);
          outf[(size_t)row * COUT_ + c] = o;
          outbf[(size_t)row * COUT_ + c] = bf16r(o);
        } else {
          float o = fmaxf(fmaf(v, g, b) + resf[(size_t)row * COUT_ + c], 0.f);
          outbf[(size_t)row * COUT_ + c] = bf16r(o);
        }
      }
    }
  }
}

// ---------------------------------------------------------------------------
extern "C" void kernel_launch(void* const* d_in, const int* in_sizes, int n_in,
                              void* d_out, int out_size, void* d_ws, size_t ws_size,
                              hipStream_t stream) {
  const float* x3d  = (const float*)d_in[0];
  const float* f2d  = (const float*)d_in[1];
  const int*   nn   = (const int*)d_in[2];
  const int*   nbr  = (const int*)d_in[3];
  const int*   nbds = (const int*)d_in[4];
  const float* W3d  = (const float*)d_in[5];
  const float* g3d  = (const float*)d_in[6];
  const float* b3d  = (const float*)d_in[7];
  const float* Wg   = (const float*)d_in[8];
  const float* bg   = (const float*)d_in[9];
  const float* Wc   = (const float*)d_in[10];
  const float* bc   = (const float*)d_in[11];
  const float* Wp   = (const float*)d_in[12];
  const float* W2d  = (const float*)d_in[13];
  const float* g2d  = (const float*)d_in[14];
  const float* b2d  = (const float*)d_in[15];
  const float* Wm1  = (const float*)d_in[16];
  const float* gm1  = (const float*)d_in[17];
  const float* bm1  = (const float*)d_in[18];
  const float* Wm2  = (const float*)d_in[19];
  const float* gm2  = (const float*)d_in[20];
  const float* bm2  = (const float*)d_in[21];
  const float* Wa1  = (const float*)d_in[22];
  const float* ga1  = (const float*)d_in[23];
  const float* ba1  = (const float*)d_in[24];
  const float* Wa2  = (const float*)d_in[25];
  const float* ga2  = (const float*)d_in[26];
  const float* ba2  = (const float*)d_in[27];
  const float* Wds  = (const float*)d_in[28];
  const float* gds  = (const float*)d_in[29];
  const float* bds  = (const float*)d_in[30];

  const size_t N = NPTS;
  float* ws = (float*)d_ws;
  float* y3d     = ws;                    // N*16
  short* p2dbf   = (short*)(ws + N * 16); // N*64 bf16
  float* cross2d = ws + N * 48;           // N*64
  float* mix     = ws + N * 112;          // N*80
  short* mixbf   = (short*)(ws + N * 192);// N*80 bf16
  short* tmp1bf  = (short*)(ws + N * 232);// N*80 bf16
  float* hbuf    = ws + N * 272;          // N*80
  short* hbufbf  = (short*)(ws + N * 352);// N*80 bf16
  short* abufbf  = (short*)ws;            // N*80 bf16 (reuses y3d+p2dbf)
  // fragment-ordered bf16 weights at tail
  short* wtail  = (short*)(ws + N * 392);
  short* WbfF2d = wtail;                   // 27*2*4*512 = 110592
  short* WbfFm1 = WbfF2d + 110592;         // 27*3*5*512 = 207360
  short* WbfFm2 = WbfFm1 + 207360;
  short* WbfFa1 = WbfFm2 + 207360;
  short* WbfFa2 = WbfFa1 + 207360;
  short* WbfFds = WbfFa2 + 207360;         // 27*3*6*512 = 248832
  short* WpF    = WbfFds + 248832;         // 18432

  // ---- weight prep ----
  wfrag_kernel<<<(110592 + 255) / 256, 256, 0, stream>>>(W2d, WbfF2d, 64, 64, 2);
  wfrag_kernel<<<(207360 + 255) / 256, 256, 0, stream>>>(Wm1, WbfFm1, 80, 80, 3);
  wfrag_kernel<<<(207360 + 255) / 256, 256, 0, stream>>>(Wm2, WbfFm2, 80, 80, 3);
  wfrag_kernel<<<(207360 + 255) / 256, 256, 0, stream>>>(Wa1, WbfFa1, 80, 80, 3);
  wfrag_kernel<<<(207360 + 255) / 256, 256, 0, stream>>>(Wa2, WbfFa2, 80, 80, 3);
  wfrag_kernel<<<(248832 + 255) / 256, 256, 0, stream>>>(Wds, WbfFds, 80, 96, 3);
  wpfrag_kernel<<<(9 * 4 * 64 * 8 + 255) / 256, 256, 0, stream>>>(Wp, WpF);

  conv3d_bnrelu_kernel<<<NPTS / 16, 256, 0, stream>>>(x3d, nbr, W3d, g3d, b3d,
                                                      y3d, mix, mixbf);
  gate_cross_mfma_kernel<<<NPTS / 32, 256, 0, stream>>>(y3d, f2d, nn, Wg, bg,
                                                        Wc, bc, WpF, p2dbf,
                                                        cross2d);

  const int gridN = (NPTS + 127) / 128;    // 625
  conv_db_kernel<64, 64, 2, 4><<<gridN, 256, 0, stream>>>(
      p2dbf, nbr, NPTS, WbfF2d, g2d, b2d, cross2d, mix, mixbf);
  conv_db_kernel<80, 80, 1, 3><<<gridN, 256, 0, stream>>>(
      mixbf, nbr, NPTS, WbfFm1, gm1, bm1, nullptr, nullptr, tmp1bf);
  conv_db_kernel<80, 80, 3, 3><<<gridN, 256, 0, stream>>>(
      tmp1bf, nbr, NPTS, WbfFm2, gm2, bm2, mix, hbuf, hbufbf);
  conv_db_kernel<80, 80, 1, 3><<<gridN, 256, 0, stream>>>(
      hbufbf, nbr, NPTS, WbfFa1, ga1, ba1, nullptr, nullptr, tmp1bf);
  conv_db_kernel<80, 80, 4, 3><<<gridN, 256, 0, stream>>>(
      tmp1bf, nbr, NPTS, WbfFa2, ga2, ba2, hbuf, nullptr, abufbf);

  const int gridND = (NDPTS + 127) / 128;  // 79
  conv_db_kernel<80, 96, 0, 3><<<gridND, 256, 0, stream>>>(
      abufbf, nbds, NDPTS, WbfFds, gds, bds, nullptr, (float*)d_out, nullptr);
}